// Round 13
// baseline (119.663 us; speedup 1.0000x reference)
//
#include <hip/hip_runtime.h>
#include <hip/hip_bf16.h>

#define IN_F   4096
#define OUT_F  4096
#define QBLK   8
#define NBLKS  512
#define NTOK   1024
#define NCENT  2048

#define SPLITK 4
#define KCHUNK (IN_F / SPLITK)   // 1024
#define KITERS (KCHUNK / 32)     // 32

typedef unsigned int u32;
typedef unsigned short u16;
typedef __attribute__((ext_vector_type(8))) short short8;   // 8 bf16 (MFMA A/B frag)
typedef __attribute__((ext_vector_type(4))) float floatx4;  // MFMA C/D frag

// round-to-nearest-even fp32 -> bf16
__device__ __forceinline__ u16 f2bf(float f) {
  union { float f; u32 u; } v; v.f = f;
  u32 u = v.u;
  return (u16)((u + 0x7fffu + ((u >> 16) & 1u)) >> 16);
}

__device__ __forceinline__ void load_lds_16(const void* g, void* l) {
  __builtin_amdgcn_global_load_lds(
      (const __attribute__((address_space(1))) u32*)g,
      (__attribute__((address_space(3))) u32*)l, 16, 0, 0);
}

// ---------------------------------------------------------------------------
// cast fp32 -> bf16 (plain layout) -- used for centroids only
// ---------------------------------------------------------------------------
__global__ __launch_bounds__(256) void cast_bf16_kernel(
    const float* __restrict__ src, u16* __restrict__ dst) {
  int g = blockIdx.x * 256 + threadIdx.x;   // one 8-element chunk
  const float4* sv = (const float4*)src;
  float4 a = sv[(size_t)g * 2];
  float4 b = sv[(size_t)g * 2 + 1];
  union { u16 s[8]; uint4 v; } o;
  o.s[0] = f2bf(a.x); o.s[1] = f2bf(a.y); o.s[2] = f2bf(a.z); o.s[3] = f2bf(a.w);
  o.s[4] = f2bf(b.x); o.s[5] = f2bf(b.y); o.s[6] = f2bf(b.z); o.s[7] = f2bf(b.w);
  ((uint4*)dst)[g] = o.v;
}

// ---------------------------------------------------------------------------
// pack assignments int32 -> u16 (NCENT=2048 < 2^16, lossless). Halves the
// assign stream 8 MB -> 4 MB so an XCD's (x-slice + assign-slice) working
// set fits its 4 MB L2 under the 2-D swizzle below.
// ---------------------------------------------------------------------------
__global__ __launch_bounds__(256) void cast_idx_kernel(
    const int* __restrict__ src, u16* __restrict__ dst) {
  int g = blockIdx.x * 256 + threadIdx.x;   // one 8-element chunk
  int4 a = ((const int4*)src)[(size_t)g * 2];
  int4 b = ((const int4*)src)[(size_t)g * 2 + 1];
  union { u16 s[8]; uint4 v; } o;
  o.s[0] = (u16)a.x; o.s[1] = (u16)a.y; o.s[2] = (u16)a.z; o.s[3] = (u16)a.w;
  o.s[4] = (u16)b.x; o.s[5] = (u16)b.y; o.s[6] = (u16)b.z; o.s[7] = (u16)b.w;
  ((uint4*)dst)[g] = o.v;
}

// ---------------------------------------------------------------------------
// cast x fp32 -> bf16 in MFMA-fragment-ordered layout:
//   elem (m,k) -> [(m>>4)*512 + (k>>3)]*128 + (m&15)*8 + (k&7)
// A wave's A-fragment load becomes ONE contiguous 1 KB global_load_dwordx4.
// ---------------------------------------------------------------------------
__global__ __launch_bounds__(256) void cast_swz_kernel(
    const float* __restrict__ src, u16* __restrict__ dst) {
  __shared__ __align__(16) u16 ls[256 * 8];      // 256 chunks of 16 B = 4 KB
  const int b = blockIdx.x;
  const int mg = b >> 5;          // m-group 0..63
  const int kq = b & 31;          // k-chunk of 128 elems, 0..31
  const int t = threadIdx.x;
  const int ml = t >> 4;          // m within group 0..15
  const int kbl = t & 15;         // quant block within chunk 0..15

  const float* p = src + (size_t)(mg * 16 + ml) * IN_F + kq * 128 + kbl * 8;
  float4 a = ((const float4*)p)[0];
  float4 c = ((const float4*)p)[1];
  union { u16 s[8]; uint4 v; } o;
  o.s[0] = f2bf(a.x); o.s[1] = f2bf(a.y); o.s[2] = f2bf(a.z); o.s[3] = f2bf(a.w);
  o.s[4] = f2bf(c.x); o.s[5] = f2bf(c.y); o.s[6] = f2bf(c.z); o.s[7] = f2bf(c.w);

  const int cidx = (kbl << 4) | (ml ^ kbl);      // bank-spread slot
  *(uint4*)&ls[cidx * 8] = o.v;
  __syncthreads();

  const int g = (t & 0xF0) | ((t & 15) ^ ((t >> 4) & 15));
  uint4* dbase = (uint4*)(dst + (size_t)(mg * 512 + kq * 16) * 128);
  dbase[g] = ((const uint4*)ls)[t];
}

// ---------------------------------------------------------------------------
// Fused GEMM, on-chip split-K, 2 blocks/CU (R12 verbatim) -- vs R12 only the
// XCD swizzle and assign dtype change:
//  * assign is u16 (4 MB total), loaded per-lane and zero-extended.
//  * 2-D XCD swizzle: XCD c = id&7 owns (m-group c>>1: 256 rows, 2 MB x) x
//    (n-half c&1: 2048 cols, 2 MB u16 assign) = 4 MB working set = one L2.
//    R12's m-band swizzle forced every XCD to stream ALL 8 MB of int32
//    assign from HBM (FETCH 37 MB); now both operand streams are L2 hits,
//    shortening the idx -> gather -> MFMA dependency chain head from
//    ~900-cyc HBM misses to ~200-cyc L2 hits.
//    decode: sub=id>>3; m0=(c>>1)*256+(sub&1)*128; n0=(c&1)*2048+(sub>>1)*64
//    (bijective over 512 blocks).
// One block = 128x64 tile, 8 waves = 4 K-groups x 2 wm; per-wave 64x64
// acc[4][4] K-loop; epilogue: 4-step LDS reduce (Cs[128][68] padded) + bias
// + float4 store. Summation order s0+s1+s2+s3 -> bitwise-same output.
//   C[m][n] = sum_k x[m][k] * centroids[assign[(k/8)*OUT_F+n]][k%8] + bias
// ---------------------------------------------------------------------------
__global__ __launch_bounds__(512, 4) void gemm_fused_kernel(
    const u16* __restrict__ xs,     // x bf16, fragment-ordered [64][512][16][8]
    const u16* __restrict__ centb,  // [NCENT][8] bf16
    const u16* __restrict__ assign, // [NBLKS*OUT_F] block-major, u16
    const float* __restrict__ bias,
    float* __restrict__ out) {      // [NTOK][OUT_F]
  __shared__ __align__(16) u16 cs[NCENT * 8];    // 32 KB centroid table
  __shared__ __align__(16) float Cs[128 * 68];   // 34.8 KB reduce buffer

  // 2-D XCD swizzle (id%8 = XCD under linear round-robin dispatch)
  const int id = blockIdx.x;
  const int c = id & 7;
  const int sub = id >> 3;                   // 0..63
  const int m0 = (c >> 1) * 256 + (sub & 1) * 128;
  const int n0 = (c & 1) * 2048 + (sub >> 1) * 64;

  const int t = threadIdx.x;
  const int lane = t & 63;
  const int wv = t >> 6;            // 0..7
  const int s = wv >> 1;            // K-chunk group 0..3
  const int wm = wv & 1;            // row half
  const int quad = lane >> 4;
  const int r16 = lane & 15;
  const int kb0 = s * (KCHUNK >> 3);       // first quant block of this chunk

  // stage centroid table: 2048 chunks of 16B = 4 per thread (DMA, no VGPR)
#pragma unroll
  for (int it = 0; it < 4; ++it) {
    int cc = it * 512 + t;
    load_lds_16(centb + (size_t)cc * 8, cs + (size_t)cc * 8);
  }

  floatx4 acc[4][4];
#pragma unroll
  for (int i = 0; i < 4; ++i)
#pragma unroll
    for (int j = 0; j < 4; ++j)
#pragma unroll
      for (int r = 0; r < 4; ++r) acc[i][j][r] = 0.0f;

  const int ncol = n0 + r16;

  // A: uniform base (SGPR) + one per-lane u32 byte offset (proven loop)
  const char* xA = (const char*)xs +
      ((size_t)((m0 >> 4) + wm * 4) * 512 + kb0) * 256;  // uniform
  const u32 va = (u32)(quad * 256 + r16 * 16);           // per-lane bytes
  const u16* ai = assign + (size_t)kb0 * OUT_F;          // uniform
  const u32 vi = (u32)(quad * OUT_F + ncol);             // per-lane elems

  // prologue: load iter-0 A frags + indices
  short8 afc[4];
  int idxc[4];
#pragma unroll
  for (int i = 0; i < 4; ++i)
    afc[i] = *(const short8*)(xA + (va + (u32)i * 131072u));
#pragma unroll
  for (int j = 0; j < 4; ++j) idxc[j] = (int)ai[vi + (u32)(j * 16)];

  __syncthreads();   // centroid table ready

  const short8* csv = (const short8*)cs;
#pragma unroll 2
  for (int kt = 0; kt < KITERS; ++kt) {
    // prefetch next iteration's A frags + indices (uniform guard)
    short8 afn[4];
    int idxn[4];
    if (kt + 1 < KITERS) {
      const char* xk = xA + (va + (u32)((kt + 1) * 1024));
#pragma unroll
      for (int i = 0; i < 4; ++i)
        afn[i] = *(const short8*)(xk + (u32)i * 131072u);
      const u16* an = ai + (size_t)(kt + 1) * 4 * OUT_F;
#pragma unroll
      for (int j = 0; j < 4; ++j) idxn[j] = (int)an[vi + (u32)(j * 16)];
    }

    // gather B frags from LDS table (one 16 B lookup per lane per frag)
    short8 bfr[4];
#pragma unroll
    for (int j = 0; j < 4; ++j) bfr[j] = csv[idxc[j]];

#pragma unroll
    for (int i = 0; i < 4; ++i)
#pragma unroll
      for (int j = 0; j < 4; ++j)
        acc[i][j] = __builtin_amdgcn_mfma_f32_16x16x32_bf16(afc[i], bfr[j], acc[i][j], 0, 0, 0);

#pragma unroll
    for (int i = 0; i < 4; ++i) afc[i] = afn[i];
#pragma unroll
    for (int j = 0; j < 4; ++j) idxc[j] = idxn[j];
  }

  // ---- on-chip split-K reduction through LDS ----
  // C/D layout: col = r16 + j*16, row = wm*64 + quad*4 + r + i*16
  const int rbase = wm * 64 + quad * 4;
  if (s == 0) {
#pragma unroll
    for (int i = 0; i < 4; ++i)
#pragma unroll
      for (int j = 0; j < 4; ++j)
#pragma unroll
        for (int r = 0; r < 4; ++r)
          Cs[(rbase + i * 16 + r) * 68 + r16 + j * 16] = acc[i][j][r];
  }
  __syncthreads();
#pragma unroll
  for (int g = 1; g < 4; ++g) {
    if (s == g) {
#pragma unroll
      for (int i = 0; i < 4; ++i)
#pragma unroll
        for (int j = 0; j < 4; ++j)
#pragma unroll
          for (int r = 0; r < 4; ++r)
            Cs[(rbase + i * 16 + r) * 68 + r16 + j * 16] += acc[i][j][r];
    }
    __syncthreads();
  }

  // cooperative store: 4 passes x (32 rows x 16 float4), bias fused
  const int c4 = t & 15;
  const float4 b4 = ((const float4*)bias)[(n0 >> 2) + c4];
#pragma unroll
  for (int p = 0; p < 4; ++p) {
    const int rr = p * 32 + (t >> 4);
    float4 v = *(const float4*)&Cs[rr * 68 + c4 * 4];
    v.x += b4.x; v.y += b4.y; v.z += b4.z; v.w += b4.w;
    ((float4*)out)[(((size_t)(m0 + rr) * OUT_F + n0) >> 2) + c4] = v;
  }
}

extern "C" void kernel_launch(void* const* d_in, const int* in_sizes, int n_in,
                              void* d_out, int out_size, void* d_ws, size_t ws_size,
                              hipStream_t stream) {
  const float* x      = (const float*)d_in[0];  // [1024][4096] fp32
  const float* cent   = (const float*)d_in[1];  // [2048][8] fp32
  const float* bias   = (const float*)d_in[2];  // [4096] fp32
  const int*   assign = (const int*)d_in[3];    // [512*4096] int32
  float* out = (float*)d_out;

  // ws layout: xs (8 MB) | centb (32 KB) | assign16 (4 MB)
  const size_t xb_bytes   = (size_t)NTOK * IN_F * sizeof(u16);      // 8388608
  const size_t cent_bytes = (size_t)NCENT * 8 * sizeof(u16);        // 32768
  u16* xs       = (u16*)d_ws;
  u16* centb    = (u16*)((char*)d_ws + xb_bytes);
  u16* assign16 = (u16*)((char*)d_ws + xb_bytes + cent_bytes);

  hipLaunchKernelGGL(cast_swz_kernel, dim3(64 * 32), dim3(256), 0, stream, x, xs);
  hipLaunchKernelGGL(cast_bf16_kernel, dim3((NCENT * 8 / 8) / 256), dim3(256), 0, stream,
                     cent, centb);
  hipLaunchKernelGGL(cast_idx_kernel, dim3((NBLKS * OUT_F / 8) / 256), dim3(256), 0, stream,
                     assign, assign16);
  hipLaunchKernelGGL(gemm_fused_kernel, dim3(512), dim3(512), 0, stream,
                     xs, centb, assign16, bias, out);
}

// Round 14
// 115.636 us; speedup vs baseline: 1.0348x; 1.0348x over previous
//
#include <hip/hip_runtime.h>
#include <hip/hip_bf16.h>

#define IN_F   4096
#define OUT_F  4096
#define QBLK   8
#define NBLKS  512
#define NTOK   1024
#define NCENT  2048

#define SPLITK 4
#define KCHUNK (IN_F / SPLITK)   // 1024
#define KITERS (KCHUNK / 32)     // 32

typedef unsigned int u32;
typedef unsigned short u16;
typedef __attribute__((ext_vector_type(8))) short short8;   // 8 bf16 (MFMA A/B frag)
typedef __attribute__((ext_vector_type(4))) float floatx4;  // MFMA C/D frag

// round-to-nearest-even fp32 -> bf16
__device__ __forceinline__ u16 f2bf(float f) {
  union { float f; u32 u; } v; v.f = f;
  u32 u = v.u;
  return (u16)((u + 0x7fffu + ((u >> 16) & 1u)) >> 16);
}

__device__ __forceinline__ void load_lds_16(const void* g, void* l) {
  __builtin_amdgcn_global_load_lds(
      (const __attribute__((address_space(1))) u32*)g,
      (__attribute__((address_space(3))) u32*)l, 16, 0, 0);
}

// ---------------------------------------------------------------------------
// fused prep kernel (one launch):
//  blocks [0, 2048): x fp32 -> bf16 in MFMA-fragment-ordered layout
//     elem (m,k) -> [(m>>4)*512 + (k>>3)]*128 + (m&15)*8 + (k&7)
//     (wave A-frag load becomes ONE contiguous 1 KB global_load_dwordx4)
//  blocks [2048, 2056): centroids fp32 -> bf16, plain layout
// ---------------------------------------------------------------------------
__global__ __launch_bounds__(256) void cast_fused_kernel(
    const float* __restrict__ x, u16* __restrict__ xs,
    const float* __restrict__ cent, u16* __restrict__ centb) {
  const int b = blockIdx.x;
  const int t = threadIdx.x;

  if (b >= 2048) {                 // centroid cast: 2048 chunks of 8 elems
    int g = (b - 2048) * 256 + t;
    const float4* sv = (const float4*)cent;
    float4 a = sv[(size_t)g * 2];
    float4 c = sv[(size_t)g * 2 + 1];
    union { u16 s[8]; uint4 v; } o;
    o.s[0] = f2bf(a.x); o.s[1] = f2bf(a.y); o.s[2] = f2bf(a.z); o.s[3] = f2bf(a.w);
    o.s[4] = f2bf(c.x); o.s[5] = f2bf(c.y); o.s[6] = f2bf(c.z); o.s[7] = f2bf(c.w);
    ((uint4*)centb)[g] = o.v;
    return;
  }

  __shared__ __align__(16) u16 ls[256 * 8];      // 256 chunks of 16 B = 4 KB
  const int mg = b >> 5;          // m-group 0..63
  const int kq = b & 31;          // k-chunk of 128 elems, 0..31
  const int ml = t >> 4;          // m within group 0..15
  const int kbl = t & 15;         // quant block within chunk 0..15

  const float* p = x + (size_t)(mg * 16 + ml) * IN_F + kq * 128 + kbl * 8;
  float4 a = ((const float4*)p)[0];
  float4 c = ((const float4*)p)[1];
  union { u16 s[8]; uint4 v; } o;
  o.s[0] = f2bf(a.x); o.s[1] = f2bf(a.y); o.s[2] = f2bf(a.z); o.s[3] = f2bf(a.w);
  o.s[4] = f2bf(c.x); o.s[5] = f2bf(c.y); o.s[6] = f2bf(c.z); o.s[7] = f2bf(c.w);

  const int cidx = (kbl << 4) | (ml ^ kbl);      // bank-spread slot
  *(uint4*)&ls[cidx * 8] = o.v;
  __syncthreads();

  const int g = (t & 0xF0) | ((t & 15) ^ ((t >> 4) & 15));
  uint4* dbase = (uint4*)(xs + (size_t)(mg * 512 + kq * 16) * 128);
  dbase[g] = ((const uint4*)ls)[t];
}

// ---------------------------------------------------------------------------
// Fused GEMM, on-chip split-K, 2 blocks/CU -- R12 VERBATIM (best measured
// total: 116.9 us; gemm 43.4-44.8 us, WRITE 16 MB, MfmaUtil ~31).
// One block = one 128x64 output tile, 8 waves = 4 K-chunk groups x 2
// wm-waves; each wave runs the proven 64x64 acc[4][4] barrier-free K-loop
// over its group's 1024-K chunk. LDS 66.8 KB/block (32K table + 128x68
// padded Cs) -> 2 blocks co-resident/CU (regs 128 -> 16 waves/CU); the two
// blocks' K-loops and epilogues interleave (m114 overlap at block scope).
// Epilogue: groups 0..3 sum accumulators through Cs (4-step serial LDS
// reduce, summation order s0+s1+s2+s3 = bitwise-same as old reduce pass),
// then cooperative bias + float4 store. No partials, no reduce kernel, no
// atomics (R2: 4B device-scope RMWs write through HBM).
// XCD swizzle: id&7 = m-band (1 MB x-slice L2-resident per XCD). The
// FETCH-optimal variants (R8 12.6 MB, R13 u16+2D) were A/B'd: <=2 us --
// not worth an extra launch or unproven decode.
//   C[m][n] = sum_k x[m][k] * centroids[assign[(k/8)*OUT_F+n]][k%8] + bias
// ---------------------------------------------------------------------------
__global__ __launch_bounds__(512, 4) void gemm_fused_kernel(
    const u16* __restrict__ xs,     // x bf16, fragment-ordered [64][512][16][8]
    const u16* __restrict__ centb,  // [NCENT][8] bf16
    const int* __restrict__ assign, // [NBLKS*OUT_F] block-major
    const float* __restrict__ bias,
    float* __restrict__ out) {      // [NTOK][OUT_F]
  __shared__ __align__(16) u16 cs[NCENT * 8];    // 32 KB centroid table
  __shared__ __align__(16) float Cs[128 * 68];   // 34.8 KB reduce buffer

  // XCD swizzle: id%8 = XCD under linear round-robin dispatch
  const int id = blockIdx.x;
  const int m0 = (id & 7) * 128;    // one m-band per XCD
  const int n0 = (id >> 3) * 64;    // 64 n-tiles

  const int t = threadIdx.x;
  const int lane = t & 63;
  const int wv = t >> 6;            // 0..7
  const int s = wv >> 1;            // K-chunk group 0..3
  const int wm = wv & 1;            // row half
  const int quad = lane >> 4;
  const int r16 = lane & 15;
  const int kb0 = s * (KCHUNK >> 3);       // first quant block of this chunk

  // stage centroid table: 2048 chunks of 16B = 4 per thread (DMA, no VGPR)
#pragma unroll
  for (int it = 0; it < 4; ++it) {
    int c = it * 512 + t;
    load_lds_16(centb + (size_t)c * 8, cs + (size_t)c * 8);
  }

  floatx4 acc[4][4];
#pragma unroll
  for (int i = 0; i < 4; ++i)
#pragma unroll
    for (int j = 0; j < 4; ++j)
#pragma unroll
      for (int r = 0; r < 4; ++r) acc[i][j][r] = 0.0f;

  const int ncol = n0 + r16;

  // A: uniform base (SGPR) + one per-lane u32 byte offset (proven loop)
  const char* xA = (const char*)xs +
      ((size_t)((m0 >> 4) + wm * 4) * 512 + kb0) * 256;  // uniform
  const u32 va = (u32)(quad * 256 + r16 * 16);           // per-lane bytes
  const int* ai = assign + (size_t)kb0 * OUT_F;          // uniform
  const u32 vi = (u32)(quad * OUT_F + ncol);             // per-lane elems

  // prologue: load iter-0 A frags + indices
  short8 afc[4];
  int idxc[4];
#pragma unroll
  for (int i = 0; i < 4; ++i)
    afc[i] = *(const short8*)(xA + (va + (u32)i * 131072u));
#pragma unroll
  for (int j = 0; j < 4; ++j) idxc[j] = ai[vi + (u32)(j * 16)];

  __syncthreads();   // centroid table ready

  const short8* csv = (const short8*)cs;
#pragma unroll 2
  for (int kt = 0; kt < KITERS; ++kt) {
    // prefetch next iteration's A frags + indices (uniform guard)
    short8 afn[4];
    int idxn[4];
    if (kt + 1 < KITERS) {
      const char* xk = xA + (va + (u32)((kt + 1) * 1024));
#pragma unroll
      for (int i = 0; i < 4; ++i)
        afn[i] = *(const short8*)(xk + (u32)i * 131072u);
      const int* an = ai + (size_t)(kt + 1) * 4 * OUT_F;
#pragma unroll
      for (int j = 0; j < 4; ++j) idxn[j] = an[vi + (u32)(j * 16)];
    }

    // gather B frags from LDS table (one 16 B lookup per lane per frag)
    short8 bfr[4];
#pragma unroll
    for (int j = 0; j < 4; ++j) bfr[j] = csv[idxc[j]];

#pragma unroll
    for (int i = 0; i < 4; ++i)
#pragma unroll
      for (int j = 0; j < 4; ++j)
        acc[i][j] = __builtin_amdgcn_mfma_f32_16x16x32_bf16(afc[i], bfr[j], acc[i][j], 0, 0, 0);

#pragma unroll
    for (int i = 0; i < 4; ++i) afc[i] = afn[i];
#pragma unroll
    for (int j = 0; j < 4; ++j) idxc[j] = idxn[j];
  }

  // ---- on-chip split-K reduction through LDS ----
  // C/D layout: col = r16 + j*16, row = wm*64 + quad*4 + r + i*16
  const int rbase = wm * 64 + quad * 4;
  if (s == 0) {
#pragma unroll
    for (int i = 0; i < 4; ++i)
#pragma unroll
      for (int j = 0; j < 4; ++j)
#pragma unroll
        for (int r = 0; r < 4; ++r)
          Cs[(rbase + i * 16 + r) * 68 + r16 + j * 16] = acc[i][j][r];
  }
  __syncthreads();
#pragma unroll
  for (int g = 1; g < 4; ++g) {
    if (s == g) {
#pragma unroll
      for (int i = 0; i < 4; ++i)
#pragma unroll
        for (int j = 0; j < 4; ++j)
#pragma unroll
          for (int r = 0; r < 4; ++r)
            Cs[(rbase + i * 16 + r) * 68 + r16 + j * 16] += acc[i][j][r];
    }
    __syncthreads();
  }

  // cooperative store: 4 passes x (32 rows x 16 float4), bias fused
  const int c4 = t & 15;
  const float4 b4 = ((const float4*)bias)[(n0 >> 2) + c4];
#pragma unroll
  for (int p = 0; p < 4; ++p) {
    const int rr = p * 32 + (t >> 4);
    float4 v = *(const float4*)&Cs[rr * 68 + c4 * 4];
    v.x += b4.x; v.y += b4.y; v.z += b4.z; v.w += b4.w;
    ((float4*)out)[(((size_t)(m0 + rr) * OUT_F + n0) >> 2) + c4] = v;
  }
}

extern "C" void kernel_launch(void* const* d_in, const int* in_sizes, int n_in,
                              void* d_out, int out_size, void* d_ws, size_t ws_size,
                              hipStream_t stream) {
  const float* x      = (const float*)d_in[0];  // [1024][4096] fp32
  const float* cent   = (const float*)d_in[1];  // [2048][8] fp32
  const float* bias   = (const float*)d_in[2];  // [4096] fp32
  const int*   assign = (const int*)d_in[3];    // [512*4096] int32
  float* out = (float*)d_out;

  // ws layout: xs (8 MB) | centb (32 KB)   -- no partials (on-chip reduce)
  const size_t xb_bytes = (size_t)NTOK * IN_F * sizeof(u16);      // 8388608
  u16* xs    = (u16*)d_ws;
  u16* centb = (u16*)((char*)d_ws + xb_bytes);

  hipLaunchKernelGGL(cast_fused_kernel, dim3(2048 + 8), dim3(256), 0, stream,
                     x, xs, cent, centb);
  hipLaunchKernelGGL(gemm_fused_kernel, dim3(512), dim3(512), 0, stream,
                     xs, centb, assign, bias, out);
}